// Round 1
// baseline (169.334 us; speedup 1.0000x reference)
//
#include <hip/hip_runtime.h>
#include <hip/hip_bf16.h>

// CIN (xDeepFM) fused 3-layer kernel for MI355X.
// B=1024, F0=32, D=32, H=128 per layer.
// Layer: h[b,d,h] = sum_{f,g} x0[b,f,d]*S[b,g,d]*W[f*Fk+g,h] + bias[h]
// One WG owns 4 batches (128 rows = (b,d)); all 3 layers run locally with
// LDS-resident state (layer dep is per-batch). A-frags built in registers as
// (cached S rows) * (per-lane scalar x0[b,f,d]); B-frags from LDS-staged,
// pre-packed bf16 W tiles (packed by a prologue kernel into d_ws).

typedef __attribute__((ext_vector_type(8))) short short8;
typedef __attribute__((ext_vector_type(8))) __bf16 bf16x8;
typedef __attribute__((ext_vector_type(16))) float f32x16;

#define DEVINL static __device__ __forceinline__

// round-to-nearest-even f32 -> bf16 bits (finite inputs only)
DEVINL unsigned short f2bf_rne(float f) {
  unsigned int u = __builtin_bit_cast(unsigned int, f);
  unsigned int r = u + 0x7fffu + ((u >> 16) & 1u);
  return (unsigned short)(r >> 16);
}
DEVINL float bf2f(unsigned short u) {
  unsigned int x = ((unsigned int)u) << 16;
  return __builtin_bit_cast(float, x);
}

// async global->LDS, 16B per lane; LDS dest = uniform base + lane*16
DEVINL void gload_lds16(const unsigned short* g, unsigned short* l) {
  __builtin_amdgcn_global_load_lds(
      (const __attribute__((address_space(1))) unsigned int*)g,
      (__attribute__((address_space(3))) unsigned int*)l, 16, 0, 0);
}

// MFMA adapter: builtin may want v8i16 (guide) or v8bf16 (LLVM td). SFINAE both.
template <typename V>
DEVINL auto mfma_32x32x16_bf16(V a, V b, f32x16 c, int)
    -> decltype(__builtin_amdgcn_mfma_f32_32x32x16_bf16(a, b, c, 0, 0, 0)) {
  return __builtin_amdgcn_mfma_f32_32x32x16_bf16(a, b, c, 0, 0, 0);
}
template <typename V>
DEVINL f32x16 mfma_32x32x16_bf16(V a, V b, f32x16 c, long) {
  return __builtin_amdgcn_mfma_f32_32x32x16_bf16(
      __builtin_bit_cast(bf16x8, a), __builtin_bit_cast(bf16x8, b), c, 0, 0, 0);
}
DEVINL f32x16 mfma_bf16(short8 a, short8 b, f32x16 c) {
  return mfma_32x32x16_bf16(a, b, c, 0);
}

// ---------------- W pack kernel ----------------
// Packed layout per layer, per f-tile: [f][kb = kk>>3][h][kk&7] bf16, where
// kk in [0,FK) is g within f's K-block, h in [0,128). This makes LDS staging a
// pure linear copy AND B-frag ds_read_b128 reads contiguous (per lane: fixed
// h row, 8 consecutive kk). Totals: L0 131072, L1 524288, L2 524288 elems.
__global__ void pack_w_kernel(const float* __restrict__ W0,
                              const float* __restrict__ W1,
                              const float* __restrict__ W2,
                              unsigned short* __restrict__ Wt) {
  const int idx = blockIdx.x * 256 + threadIdx.x;
  const float* W;
  int FK, base, fshift;
  if (idx < 131072)      { W = W0; FK = 32;  base = 0;      fshift = 12; }
  else if (idx < 655360) { W = W1; FK = 128; base = 131072; fshift = 14; }
  else                   { W = W2; FK = 128; base = 655360; fshift = 14; }
  const int r  = idx - base;
  const int j  = r & 7;
  const int h  = (r >> 3) & 127;
  const int kb = (r >> 10) & (FK / 8 - 1);
  const int f  = r >> fshift;
  const int kk = kb * 8 + j;
  Wt[idx] = f2bf_rne(W[(f * FK + kk) * 128 + h]);
}

// ---------------- main kernel helpers ----------------
template <int CPW>
DEVINL void stage_piece(const unsigned short* __restrict__ src,
                        unsigned short* dst, int w, int lane) {
  // piece = CPW*4 chunks of 512 elems (1KB); wave w stages its CPW chunks
#pragma unroll
  for (int c = 0; c < CPW; ++c) {
    const int chunk = w * CPW + c;
    gload_lds16(src + chunk * 512 + lane * 8, dst + chunk * 512);
  }
}

// One staged piece = granules (kql*2+half) for kql in [0,KQN); kq = KQB+kql.
template <int KQ, int KQB, int KQN>
DEVINL void compute_block(const unsigned short* __restrict__ Wb,
                          const float (&sF)[2][KQ][8],
                          float xs0, float xs1,
                          f32x16 (&acc0)[2], f32x16 (&acc1)[2],
                          int wc, int l31, int half) {
#pragma unroll
  for (int kql = 0; kql < KQN; ++kql) {
    const int kq = KQB + kql;  // compile-time constant after unroll
    union { short8 v; unsigned int u[4]; } a0, a1;
#pragma unroll
    for (int jj = 0; jj < 4; ++jj) {
      // z element = S * x0 scale, truncate-pack to bf16 pairs (cheap; error
      // budget is ~1.86 abs, truncation bias ~0.2%/layer)
      float p0 = sF[0][kq][2 * jj] * xs0;
      float p1 = sF[0][kq][2 * jj + 1] * xs0;
      a0.u[jj] = (__builtin_bit_cast(unsigned int, p0) >> 16) |
                 (__builtin_bit_cast(unsigned int, p1) & 0xffff0000u);
      float q0 = sF[1][kq][2 * jj] * xs1;
      float q1 = sF[1][kq][2 * jj + 1] * xs1;
      a1.u[jj] = (__builtin_bit_cast(unsigned int, q0) >> 16) |
                 (__builtin_bit_cast(unsigned int, q1) & 0xffff0000u);
    }
#pragma unroll
    for (int nt = 0; nt < 2; ++nt) {
      const short8 bfr = *(const short8*)&Wb[(unsigned)((kql * 2 + half) * 1024 +
                                                        (wc * 64 + nt * 32 + l31) * 8)];
      acc0[nt] = mfma_bf16(a0.v, bfr, acc0[nt]);
      acc1[nt] = mfma_bf16(a1.v, bfr, acc1[nt]);
    }
  }
}

template <int FK>
DEVINL void run_layer(const unsigned short* __restrict__ Wt,
                      const float* __restrict__ bias,
                      const float* __restrict__ x0g, int xb0,
                      float* __restrict__ outp,
                      unsigned short* Slds,
                      unsigned short* Wb0, unsigned short* Wb1,
                      int w, int lane, int l31, int half, int wr, int wc,
                      bool writeState) {
  constexpr int KQ = FK / 16;

  __syncthreads();  // state S ready; previous layer fully done with W bufs

  // Preload this wave's S fragments (rows = wr*64+mt*32+l31, all K) as f32.
  float sF[2][KQ][8];
#pragma unroll
  for (int mt = 0; mt < 2; ++mt) {
    const int r = wr * 64 + mt * 32 + l31;  // r = b_local*32 + d
#pragma unroll
    for (int kq = 0; kq < KQ; ++kq) {
      const short8 raw = *(const short8*)&Slds[r * 128 + kq * 16 + half * 8];
#pragma unroll
      for (int j = 0; j < 8; ++j)
        sF[mt][kq][j] = bf2f((unsigned short)raw[j]);
    }
  }

  f32x16 acc0[2], acc1[2];
#pragma unroll
  for (int nt = 0; nt < 2; ++nt)
#pragma unroll
    for (int e = 0; e < 16; ++e) { acc0[nt][e] = 0.f; acc1[nt][e] = 0.f; }

  float xs0c = x0g[xb0];          // x0[b(mt=0), f=0, d=l31]
  float xs1c = x0g[xb0 + 1024];   // x0[b(mt=1), f=0, d=l31]

  if constexpr (FK == 128) {
    stage_piece<4>(Wt, Wb0, w, lane);  // piece 0 (f=0, kq 0..3)
#pragma unroll 1
    for (int f = 0; f < 32; ++f) {
      __syncthreads();  // piece in Wb0 ready (implicit vmcnt(0)); Wb1 free
      stage_piece<4>(Wt + (size_t)(2 * f + 1) * 8192, Wb1, w, lane);
      float xs0n = xs0c, xs1n = xs1c;
      if (f < 31) {  // prefetch next f's x0 scales (latency hidden by compute)
        xs0n = x0g[xb0 + (f + 1) * 32];
        xs1n = x0g[xb0 + 1024 + (f + 1) * 32];
      }
      compute_block<KQ, 0, 4>(Wb0, sF, xs0c, xs1c, acc0, acc1, wc, l31, half);
      __syncthreads();
      if (f < 31) stage_piece<4>(Wt + (size_t)(2 * f + 2) * 8192, Wb0, w, lane);
      compute_block<KQ, 4, 4>(Wb1, sF, xs0c, xs1c, acc0, acc1, wc, l31, half);
      xs0c = xs0n; xs1c = xs1n;
    }
  } else {
    stage_piece<2>(Wt, Wb0, w, lane);  // full 8KB f-tile per piece
#pragma unroll 1
    for (int f = 0; f < 32; ++f) {
      __syncthreads();
      unsigned short* nbuf = ((f & 1) == 0) ? Wb1 : Wb0;
      const unsigned short* cbuf = ((f & 1) == 0) ? Wb0 : Wb1;
      if (f < 31) stage_piece<2>(Wt + (size_t)(f + 1) * 4096, nbuf, w, lane);
      float xs0n = xs0c, xs1n = xs1c;
      if (f < 31) {
        xs0n = x0g[xb0 + (f + 1) * 32];
        xs1n = x0g[xb0 + 1024 + (f + 1) * 32];
      }
      compute_block<KQ, 0, 2>(cbuf, sF, xs0c, xs1c, acc0, acc1, wc, l31, half);
      xs0c = xs0n; xs1c = xs1n;
    }
  }

  // Epilogue: C/D layout (verified): col = lane&31, row = (reg&3)+8*(reg>>2)+4*half.
  // out[b, l*128+h] = sum_d (acc+bias); next state S[b][d][h] = bf16(acc+bias).
#pragma unroll
  for (int mt = 0; mt < 2; ++mt) {
#pragma unroll
    for (int nt = 0; nt < 2; ++nt) {
      const int hc = wc * 64 + nt * 32 + l31;
      const float bv = bias[hc];
      float part = 0.f;
#pragma unroll
      for (int reg = 0; reg < 16; ++reg) {
        const int d = (reg & 3) + 8 * (reg >> 2) + 4 * half;
        const float v = ((mt == 0) ? acc0[nt][reg] : acc1[nt][reg]) + bv;
        part += v;
        if (writeState)
          Slds[((wr * 2 + mt) * 32 + d) * 128 + hc] = f2bf_rne(v);
      }
      part += __shfl_xor(part, 32, 64);  // combine the two half-wave row sets
      if (half == 0)
        outp[(wr * 2 + mt) * 384 + hc] = part;
    }
  }
}

__global__ __launch_bounds__(256, 1) void cin_kernel(
    const float* __restrict__ x0g, const unsigned short* __restrict__ Wt,
    const float* __restrict__ b0, const float* __restrict__ b1,
    const float* __restrict__ b2, float* __restrict__ out) {
  // exactly 64KB static LDS
  __shared__ __align__(16) unsigned short Wb0[8192];        // 16KB W piece buf A
  __shared__ __align__(16) unsigned short Wb1[8192];        // 16KB W piece buf B
  __shared__ __align__(16) unsigned short Slds[4 * 32 * 128];  // 32KB state bf16

  const int t = threadIdx.x;
  const int lane = t & 63;
  const int w = t >> 6;
  const int wr = w >> 1, wc = w & 1;  // 2x2 wave grid over 128x128 C tile
  const int l31 = lane & 31, half = lane >> 5;
  const int wgb0 = blockIdx.x * 4;  // 4 batches per WG

  // init S0[b][d][g] = x0[b][g][d] (g<32), bf16, row stride 128
  if (t < 128) {
    const int b = t >> 5, d = t & 31;
#pragma unroll
    for (int g = 0; g < 32; ++g)
      Slds[t * 128 + g] = f2bf_rne(x0g[(wgb0 + b) * 1024 + g * 32 + d]);
  }

  const int xb0 = (wgb0 + wr * 2) * 1024 + l31;  // x0[b(mt=0)][f=0][d=l31]
  float* outp = out + (size_t)wgb0 * 384;

  run_layer<32>(Wt, b0, x0g, xb0, outp, Slds, Wb0, Wb1,
                w, lane, l31, half, wr, wc, true);
  run_layer<128>(Wt + 131072, b1, x0g, xb0, outp + 128, Slds, Wb0, Wb1,
                 w, lane, l31, half, wr, wc, true);
  run_layer<128>(Wt + 655360, b2, x0g, xb0, outp + 256, Slds, Wb0, Wb1,
                 w, lane, l31, half, wr, wc, false);
}

extern "C" void kernel_launch(void* const* d_in, const int* in_sizes, int n_in,
                              void* d_out, int out_size, void* d_ws, size_t ws_size,
                              hipStream_t stream) {
  (void)in_sizes; (void)n_in; (void)out_size; (void)ws_size;
  const float* x0 = (const float*)d_in[0];
  const float* W0 = (const float*)d_in[1];
  const float* W1 = (const float*)d_in[2];
  const float* W2 = (const float*)d_in[3];
  const float* b0 = (const float*)d_in[4];
  const float* b1 = (const float*)d_in[5];
  const float* b2 = (const float*)d_in[6];
  unsigned short* Wt = (unsigned short*)d_ws;  // needs 2,359,296 B

  // pack W -> bf16 fragment-ready layout (rewrites all of Wt every call;
  // d_ws is re-poisoned before each timed launch)
  pack_w_kernel<<<4608, 256, 0, stream>>>(W0, W1, W2, Wt);
  // fused 3-layer CIN: 256 WGs (1/CU), 4 waves each
  cin_kernel<<<256, 256, 0, stream>>>(x0, Wt, b0, b1, b2, (float*)d_out);
}

// Round 2
// 166.815 us; speedup vs baseline: 1.0151x; 1.0151x over previous
//
#include <hip/hip_runtime.h>
#include <hip/hip_bf16.h>

// CIN (xDeepFM) fused 3-layer kernel for MI355X — transposed-GEMM version.
// B=1024, F0=32, D=32, H=128 per layer.
// Layer: h[b,d,h] = sum_{f,g} x0[b,f,d]*S[b,g,d]*W[f*Fk+g,h] + bias[h]
//      = sum_f x0[b,f,d] * (S(b,:,d) . W_f)[h]
// Transposed MFMA: D[m=h][n=r=(b,d)] = sum_k W_f[k,h] * S[r,k]
//   A-frag = W (LDS-staged, ds_read_b128, zero VALU)
//   B-frag = S (registers, loaded once per layer, zero per-k VALU)
//   x0 scale applied post-MFMA: outacc += xs_lane * Y_f  (64 fma / f)
// One WG owns 4 batches (r = 0..127); grid 256 = 1 WG/CU.
// LDS 64KB: Wb[0] 32KB + Wb[1] 32KB; inter-layer state transit buffer SB
// (u32 [k/2][r], bf16-pair packed) OVERLAYS Wb[1] (only live across layer
// boundaries: written at epilogue, consumed by next layer's frag load).

typedef __attribute__((ext_vector_type(8))) short short8;
typedef __attribute__((ext_vector_type(8))) __bf16 bf16x8;
typedef __attribute__((ext_vector_type(16))) float f32x16;
typedef __attribute__((ext_vector_type(4))) unsigned short u16x4;

#define DEVINL static __device__ __forceinline__

DEVINL unsigned short f2bf_rne(float f) {
  unsigned int u = __builtin_bit_cast(unsigned int, f);
  unsigned int r = u + 0x7fffu + ((u >> 16) & 1u);
  return (unsigned short)(r >> 16);
}

// async global->LDS, 16B per lane; LDS dest = uniform base + lane*16
DEVINL void gload_lds16(const unsigned short* g, unsigned short* l) {
  __builtin_amdgcn_global_load_lds(
      (const __attribute__((address_space(1))) unsigned int*)g,
      (__attribute__((address_space(3))) unsigned int*)l, 16, 0, 0);
}

// MFMA adapter: builtin may want v8i16 or v8bf16. SFINAE both.
template <typename V>
DEVINL auto mfma_32x32x16_bf16(V a, V b, f32x16 c, int)
    -> decltype(__builtin_amdgcn_mfma_f32_32x32x16_bf16(a, b, c, 0, 0, 0)) {
  return __builtin_amdgcn_mfma_f32_32x32x16_bf16(a, b, c, 0, 0, 0);
}
template <typename V>
DEVINL f32x16 mfma_32x32x16_bf16(V a, V b, f32x16 c, long) {
  return __builtin_amdgcn_mfma_f32_32x32x16_bf16(
      __builtin_bit_cast(bf16x8, a), __builtin_bit_cast(bf16x8, b), c, 0, 0, 0);
}
DEVINL f32x16 mfma_bf16(short8 a, short8 b, f32x16 c) {
  return mfma_32x32x16_bf16(a, b, c, 0);
}

// ---------------- W pack kernel (LDS tile transpose, coalesced both ways) --
// Packed layout per layer: [f][kb=k>>3][h][j=k&7] bf16.
// One WG per (layer,f,kb) unit: reads 8x128 f32 coalesced, writes 1024 u16
// coalesced (8B/lane).
__global__ void pack_w_kernel(const float* __restrict__ W0,
                              const float* __restrict__ W1,
                              const float* __restrict__ W2,
                              unsigned short* __restrict__ Wt) {
  __shared__ float tile[8][132];
  const int u = blockIdx.x;
  const float* W; int FK, f, kb, base;
  if (u < 128)      { W = W0; FK = 32;  f = u >> 2;         kb = u & 3;         base = 0; }
  else if (u < 640) { W = W1; FK = 128; f = (u - 128) >> 4; kb = (u - 128) & 15; base = 131072; }
  else              { W = W2; FK = 128; f = (u - 640) >> 4; kb = (u - 640) & 15; base = 655360; }
  const int t = threadIdx.x;
#pragma unroll
  for (int i = 0; i < 4; ++i) {
    const int e = t + i * 256;  // 0..1023
    const int kk = e >> 7, h = e & 127;
    tile[kk][h] = W[(f * FK + kb * 8 + kk) * 128 + h];
  }
  __syncthreads();
  unsigned short* dst = Wt + base + f * (FK / 8) * 1024 + kb * 1024;
  const int h = t >> 1;           // (t*4)>>3
  const int j0 = (t & 1) * 4;     // (t*4)&7
  u16x4 v;
  v.x = f2bf_rne(tile[j0 + 0][h]);
  v.y = f2bf_rne(tile[j0 + 1][h]);
  v.z = f2bf_rne(tile[j0 + 2][h]);
  v.w = f2bf_rne(tile[j0 + 3][h]);
  *(u16x4*)&dst[t * 4] = v;
}

// ---------------- main kernel ----------------
// stage one 32KB piece (16384 u16) into LDS; wave w does chunks w*8..w*8+7
DEVINL void stage32(const unsigned short* __restrict__ src, unsigned short* dst,
                    int w, int lane) {
#pragma unroll
  for (int c = 0; c < 8; ++c) {
    const int chunk = w * 8 + c;
    gload_lds16(src + chunk * 512 + lane * 8, dst + chunk * 512);
  }
}

// FK: layer K per f (32 or 128); FPP: f's per 32KB piece; LAYER: 0,1,2
template <int FK, int FPP, int LAYER>
DEVINL void run_layer(const unsigned short* __restrict__ Wt,
                      const unsigned short* __restrict__ WtNext,
                      const float* __restrict__ bias,
                      const float* __restrict__ x0g, int wgb0,
                      float* __restrict__ outp, int outoff,
                      unsigned short (*Wb)[16384],
                      int w, int lane, int l31, int half, int mrow, int ncol) {
  constexpr int KQ = FK / 16;
  constexpr int NP = 32 / FPP;  // pieces (32 f total)
  unsigned int* SB = (unsigned int*)&Wb[1][0];

  // --- load this layer's B-frags (S) from SB into registers, once ---
  // B[k][n=r]: slot (half,j) holds S[r][k = kq*16 + half*8 + j];
  // SB row k2 = k/2 packs (k even lo16, k odd hi16); addr = k2*128 + r
  // (bank = r%32 -> conflict-free across lanes).
  int4 sfr[2][KQ];
  const int rb = ncol * 64;
#pragma unroll
  for (int nt = 0; nt < 2; ++nt) {
    const int r = rb + nt * 32 + l31;
#pragma unroll
    for (int kq = 0; kq < KQ; ++kq) {
      const int row0 = kq * 8 + half * 4;
      int4 v;
      v.x = (int)SB[(row0 + 0) * 128 + r];
      v.y = (int)SB[(row0 + 1) * 128 + r];
      v.z = (int)SB[(row0 + 2) * 128 + r];
      v.w = (int)SB[(row0 + 3) * 128 + r];
      sfr[nt][kq] = v;
    }
  }
  __syncthreads();  // frags consumed by all waves; piece0 arrived (vmcnt drain)

  f32x16 outacc[2][2];
  f32x16 zv;
#pragma unroll
  for (int e = 0; e < 16; ++e) zv[e] = 0.f;
#pragma unroll
  for (int mt = 0; mt < 2; ++mt)
#pragma unroll
    for (int nt = 0; nt < 2; ++nt) outacc[mt][nt] = zv;

  const int hW = mrow * 64 + l31;  // A-frag h (+ mt*32)
  const int xbase0 = (wgb0 + ncol * 2 + 0) * 1024 + l31;
  const int xbase1 = (wgb0 + ncol * 2 + 1) * 1024 + l31;
  float xs0 = x0g[xbase0], xs1 = x0g[xbase1];  // f=0 scales

#pragma unroll 1
  for (int p = 0; p < NP; ++p) {
    if (p + 1 < NP)
      stage32(Wt + (p + 1) * 16384, &Wb[(p + 1) & 1][0], w, lane);
    const unsigned short* piece = &Wb[p & 1][0];
#pragma unroll
    for (int fi = 0; fi < FPP; ++fi) {
      const int f = p * FPP + fi;
      float xn0 = xs0, xn1 = xs1;
      if (f + 1 < 32) {  // prefetch next f's x0 scales
        xn0 = x0g[xbase0 + (f + 1) * 32];
        xn1 = x0g[xbase1 + (f + 1) * 32];
      }
      f32x16 Y[2][2];
#pragma unroll
      for (int kq = 0; kq < KQ; ++kq) {
        const int gb = fi * (KQ * 2 * 1024) + (2 * kq + half) * 1024;
        const short8 wf0 = *(const short8*)&piece[gb + (hW + 0) * 8];
        const short8 wf1 = *(const short8*)&piece[gb + (hW + 32) * 8];
        const short8 s0 = __builtin_bit_cast(short8, sfr[0][kq]);
        const short8 s1 = __builtin_bit_cast(short8, sfr[1][kq]);
        Y[0][0] = mfma_bf16(wf0, s0, kq == 0 ? zv : Y[0][0]);
        Y[0][1] = mfma_bf16(wf0, s1, kq == 0 ? zv : Y[0][1]);
        Y[1][0] = mfma_bf16(wf1, s0, kq == 0 ? zv : Y[1][0]);
        Y[1][1] = mfma_bf16(wf1, s1, kq == 0 ? zv : Y[1][1]);
      }
#pragma unroll
      for (int mt = 0; mt < 2; ++mt)
#pragma unroll
        for (int e = 0; e < 16; ++e) {
          outacc[mt][0][e] += xs0 * Y[mt][0][e];
          outacc[mt][1][e] += xs1 * Y[mt][1][e];
        }
      xs0 = xn0; xs1 = xn1;
    }
    __syncthreads();  // piece p+1 ready; buf[p&1] free for restage
  }

  // --- epilogue ---
  // C/D layout: col = lane&31 = n = r; row = (reg&3)+8*(reg>>2)+4*half = m = h.
  float bv[2][16];
#pragma unroll
  for (int mt = 0; mt < 2; ++mt)
#pragma unroll
    for (int e = 0; e < 16; ++e)
      bv[mt][e] = bias[mrow * 64 + mt * 32 + (e & 3) + 8 * (e >> 2) + 4 * half];

  if (LAYER < 2) {
    // next state S'[r][h] = bf16(acc + bias), packed [h/2][r] u32 into SB=Wb[1]
#pragma unroll
    for (int mt = 0; mt < 2; ++mt)
#pragma unroll
      for (int nt = 0; nt < 2; ++nt) {
        const int r = rb + nt * 32 + l31;
#pragma unroll
        for (int g = 0; g < 4; ++g) {
          const int hb = mrow * 64 + mt * 32 + 8 * g + 4 * half;  // even
          const float v0 = outacc[mt][nt][4 * g + 0] + bv[mt][4 * g + 0];
          const float v1 = outacc[mt][nt][4 * g + 1] + bv[mt][4 * g + 1];
          const float v2 = outacc[mt][nt][4 * g + 2] + bv[mt][4 * g + 2];
          const float v3 = outacc[mt][nt][4 * g + 3] + bv[mt][4 * g + 3];
          SB[(hb / 2) * 128 + r] =
              (unsigned)f2bf_rne(v0) | ((unsigned)f2bf_rne(v1) << 16);
          SB[(hb / 2 + 1) * 128 + r] =
              (unsigned)f2bf_rne(v2) | ((unsigned)f2bf_rne(v3) << 16);
        }
      }
    // kick next layer's piece0 into Wb[0] (disjoint from SB; overlaps epilogue)
    stage32(WtNext, &Wb[0][0], w, lane);
  }

  // final output: out[b, outoff+h] = sum_d acc + 32*bias  (d = l31 lanes)
#pragma unroll
  for (int mt = 0; mt < 2; ++mt)
#pragma unroll
    for (int nt = 0; nt < 2; ++nt) {
      float s[16];
#pragma unroll
      for (int e = 0; e < 16; ++e) {
        float v = outacc[mt][nt][e];
        v += __shfl_xor(v, 1);
        v += __shfl_xor(v, 2);
        v += __shfl_xor(v, 4);
        v += __shfl_xor(v, 8);
        v += __shfl_xor(v, 16);
        s[e] = v + 32.0f * bv[mt][e];
      }
      if (l31 == 0) {
        const int b = ncol * 2 + nt;
#pragma unroll
        for (int g = 0; g < 4; ++g) {
          const int h = mrow * 64 + mt * 32 + 8 * g + 4 * half;
          float4 o = {s[4 * g + 0], s[4 * g + 1], s[4 * g + 2], s[4 * g + 3]};
          *(float4*)&outp[b * 384 + outoff + h] = o;
        }
      }
    }

  if (LAYER < 2) __syncthreads();  // S' visible before next layer's frag load
}

__global__ __launch_bounds__(256, 1) void cin_kernel(
    const float* __restrict__ x0g, const unsigned short* __restrict__ Wt,
    const float* __restrict__ b0, const float* __restrict__ b1,
    const float* __restrict__ b2, float* __restrict__ out) {
  __shared__ __align__(16) unsigned short Wb[2][16384];  // 64KB total

  const int t = threadIdx.x;
  const int lane = t & 63;
  const int w = t >> 6;
  const int mrow = w >> 1;  // m(h)-tile of 64
  const int ncol = w & 1;   // n(r)-tile of 64
  const int l31 = lane & 31, half = lane >> 5;
  const int wgb0 = blockIdx.x * 4;

  // prologue: kick L0 piece0 -> Wb[0]; pack S1 = bf16(x0) into SB=Wb[1]
  stage32(Wt, &Wb[0][0], w, lane);
  unsigned int* SB = (unsigned int*)&Wb[1][0];
#pragma unroll
  for (int s = 0; s < 8; ++s) {
    const int i = t + s * 256;  // 0..2047
    const int r = i & 127, g2 = i >> 7;
    const float* p = &x0g[(wgb0 + (r >> 5)) * 1024 + (2 * g2) * 32 + (r & 31)];
    SB[g2 * 128 + r] =
        (unsigned)f2bf_rne(p[0]) | ((unsigned)f2bf_rne(p[32]) << 16);
  }
  __syncthreads();  // S1 visible (piece0 drain happens at run_layer's barrier)

  float* outp = out + (size_t)wgb0 * 384;

  run_layer<32, 4, 0>(Wt, Wt + 131072, b0, x0g, wgb0, outp, 0, Wb,
                      w, lane, l31, half, mrow, ncol);
  run_layer<128, 1, 1>(Wt + 131072, Wt + 655360, b1, x0g, wgb0, outp, 128, Wb,
                       w, lane, l31, half, mrow, ncol);
  run_layer<128, 1, 2>(Wt + 655360, (const unsigned short*)nullptr, b2, x0g,
                       wgb0, outp, 256, Wb, w, lane, l31, half, mrow, ncol);
}

extern "C" void kernel_launch(void* const* d_in, const int* in_sizes, int n_in,
                              void* d_out, int out_size, void* d_ws, size_t ws_size,
                              hipStream_t stream) {
  (void)in_sizes; (void)n_in; (void)out_size; (void)ws_size;
  const float* x0 = (const float*)d_in[0];
  const float* W0 = (const float*)d_in[1];
  const float* W1 = (const float*)d_in[2];
  const float* W2 = (const float*)d_in[3];
  const float* b0 = (const float*)d_in[4];
  const float* b1 = (const float*)d_in[5];
  const float* b2 = (const float*)d_in[6];
  unsigned short* Wt = (unsigned short*)d_ws;  // 2,359,296 B

  pack_w_kernel<<<1152, 256, 0, stream>>>(W0, W1, W2, Wt);
  cin_kernel<<<256, 256, 0, stream>>>(x0, Wt, b0, b1, b2, (float*)d_out);
}